// Round 5
// baseline (3610.159 us; speedup 1.0000x reference)
//
#include <hip/hip_runtime.h>
#include <math.h>

#define Bx 16
#define Cx 64
#define Hx 128
#define Wx 128
#define HWx (Hx * Wx)

#define TW 32
#define TH 8
#define CCH 8
#define HALO_W (TW + 2)
#define HALO_H (TH + 2)
#define CPLANE (HALO_H * HALO_W)          // 340
#define CHUNK_ELEMS (CCH * CPLANE)        // 2720
#define NPF ((CHUNK_ELEMS + 255) / 256)   // 11
#define NCHUNK (Cx / CCH)                 // 8

// workspace layout (float offsets)
#define WS_CWT   0                         // cwT[c*64+o]            4096
#define WS_GPACK 4096                      // gpack12[c*96+rg*12+k]  6144
#define WS_KERN  10240                     // per-b [c*36+k*4+g]     16*2304
#define WS_ATT   47104                     // per-b [c*4+r]          16*256

// ---------------- prep: hypernetwork + weight repacking (unchanged, passing) ----------------
__global__ __launch_bounds__(256)
void da_prep(const float* __restrict__ x_deg,
             const float* __restrict__ kw1,
             const float* __restrict__ kw2,
             const float* __restrict__ convw,
             const float* __restrict__ ca_w1,
             const float* __restrict__ ca_w2,
             const float* __restrict__ g1w,
             const float* __restrict__ g2w,
             float* __restrict__ ws)
{
    const int b = blockIdx.x;
    const int tid = threadIdx.x;

    if (b == Bx) {
        for (int i = tid; i < 4096; i += 256) {           // cwT[c*64+o] = convw[o*64+c]
            const int o = i >> 6, c = i & 63;
            ws[WS_CWT + c * 64 + o] = convw[o * 64 + c];
        }
        for (int i = tid; i < 6144; i += 256) {           // gpack12[c][rg=r*2+g][12]
            const int c = i / 96;
            int rem = i - c * 96;
            const int rg = rem / 12;
            const int k  = rem - rg * 12;
            const int r = rg >> 1;
            const int g = rg & 1;
            const float* src = g ? g2w : g1w;
            ws[WS_GPACK + i] = (k < 9) ? src[(r * Cx + c) * 9 + k] : 0.f;
        }
        return;
    }

    __shared__ float h1[16];
    __shared__ float a1[16];
    if (tid < 32) {
        const int j = tid & 15;
        const float* wsrc = (tid < 16) ? (kw1 + j * Cx) : (ca_w1 + j * Cx);
        float acc = 0.f;
        #pragma unroll 8
        for (int c = 0; c < Cx; ++c) acc = fmaf(x_deg[b * Cx + c], wsrc[c], acc);
        acc = acc > 0.f ? acc : 0.1f * acc;               // leaky_relu 0.1
        if (tid < 16) h1[j] = acc; else a1[j] = acc;
    }
    __syncthreads();

    for (int o4 = tid; o4 < 4 * 576; o4 += 256) {
        const int g = o4 / 576;
        const int o = o4 - g * 576;
        float acc = 0.f;
        #pragma unroll
        for (int i = 0; i < 4; ++i)
            acc = fmaf(h1[g * 4 + i], kw2[(g * 576 + o) * 4 + i], acc);
        const int c = o / 9;
        const int k = o - c * 9;
        ws[WS_KERN + b * 2304 + c * 36 + k * 4 + g] = acc;
    }
    {
        const int r = tid >> 6;
        const int c = tid & 63;
        float acc = 0.f;
        #pragma unroll
        for (int i = 0; i < 4; ++i)
            acc = fmaf(a1[r * 4 + i], ca_w2[(r * Cx + c) * 4 + i], acc);
        ws[WS_ATT + b * 256 + c * 4 + r] = 1.f / (1.f + expf(-acc));
    }
}

// ---------------- main fused kernel ----------------
__global__ __launch_bounds__(256, 2)     // cap 256 regs/wave; y[64] must stay in regs
void da_main(const float* __restrict__ x0,
             const float* __restrict__ ws,
             const float* __restrict__ g1b,
             const float* __restrict__ g2b,
             const float* __restrict__ convb,
             float* __restrict__ out)
{
    const int b  = blockIdx.z;
    const int h0 = blockIdx.y * TH;
    const int w0 = blockIdx.x * TW;
    const int tid = threadIdx.x;
    const int tx = tid & (TW - 1);
    const int ty = tid >> 5;

    __shared__ __align__(16) float sx[2][CHUNK_ELEMS];   // ping-pong x tile (halo)
    __shared__ __align__(16) float sgp[6144];            // guide weights [c][rg][12]
    __shared__ __align__(16) float scw[4096];            // cwT [c][o]
    __shared__ __align__(16) float skern[2304];          // [c][k][r]
    __shared__ float satt[256];                          // [c][r]

    // --- per-thread staging map (computed once) ---
    int goff[NPF];
    unsigned vmask = 0u;
    #pragma unroll
    for (int i = 0; i < NPF; ++i) {
        const int e = tid + i * 256;
        const int cc  = e / CPLANE;
        const int rem = e - cc * CPLANE;
        const int row = rem / HALO_W;
        const int col = rem - row * HALO_W;
        const int gh = h0 - 1 + row;
        const int gw = w0 - 1 + col;
        goff[i] = cc * HWx + gh * Wx + gw;
        if (e < CHUNK_ELEMS && (unsigned)gh < Hx && (unsigned)gw < Wx)
            vmask |= (1u << i);
    }

    const float* xb  = x0 + (size_t)b * Cx * HWx;
    const float* kws = ws + WS_KERN + b * 2304;
    const float* aws = ws + WS_ATT  + b * 256;

    // --- prologue: stage all weights + chunk 0 into LDS ---
    #pragma unroll
    for (int j = 0; j < 24; ++j) sgp[tid + j * 256] = ws[WS_GPACK + tid + j * 256];
    #pragma unroll
    for (int j = 0; j < 16; ++j) scw[tid + j * 256] = ws[WS_CWT + tid + j * 256];
    #pragma unroll
    for (int j = 0; j < 9; ++j)  skern[tid + j * 256] = kws[tid + j * 256];
    satt[tid] = aws[tid];
    {
        float pf0[NPF];
        #pragma unroll
        for (int i = 0; i < NPF; ++i)
            pf0[i] = (vmask >> i & 1u) ? xb[goff[i]] : 0.f;
        #pragma unroll
        for (int i = 0; i < NPF; ++i) {
            const int e = tid + i * 256;
            if (e < CHUNK_ELEMS) sx[0][e] = pf0[i];
        }
    }
    __syncthreads();

    // ================= PASS 1: guide convs -> argmax =================
    float ga[8];
    #pragma unroll
    for (int r = 0; r < 4; ++r) { ga[r] = g1b[r]; ga[4 + r] = g2b[r]; }

    #pragma unroll 1
    for (int ch = 0; ch < NCHUNK; ++ch) {
        const int buf = ch & 1;

        // prefetch next chunk (ch==7 prefetches chunk 0 for pass 2)
        float pf[NPF];
        {
            const int nch = (ch + 1) & (NCHUNK - 1);
            const float* src = xb + (size_t)nch * CCH * HWx;
            #pragma unroll
            for (int i = 0; i < NPF; ++i)
                pf[i] = (vmask >> i & 1u) ? src[goff[i]] : 0.f;
        }

        float pg[8] = {0.f, 0.f, 0.f, 0.f, 0.f, 0.f, 0.f, 0.f};
        #pragma unroll
        for (int cc = 0; cc < CCH; ++cc) {
            const int c = ch * CCH + cc;
            float n[9];
            #pragma unroll
            for (int kh = 0; kh < 3; ++kh)
                #pragma unroll
                for (int kw = 0; kw < 3; ++kw)
                    n[kh * 3 + kw] = sx[buf][cc * CPLANE + (ty + kh) * HALO_W + (tx + kw)];
            const float4* gpv = (const float4*)(sgp + c * 96);   // uniform b128 broadcasts
            #pragma unroll
            for (int r = 0; r < 4; ++r) {
                const float4 a0 = gpv[r * 6 + 0], a1 = gpv[r * 6 + 1], a2 = gpv[r * 6 + 2];
                const float4 b0 = gpv[r * 6 + 3], b1 = gpv[r * 6 + 4], b2 = gpv[r * 6 + 5];
                float s1 = 0.f, s2 = 0.f;      // k-ascending chains, bit-identical order
                s1 = fmaf(n[0], a0.x, s1); s1 = fmaf(n[1], a0.y, s1); s1 = fmaf(n[2], a0.z, s1);
                s1 = fmaf(n[3], a0.w, s1); s1 = fmaf(n[4], a1.x, s1); s1 = fmaf(n[5], a1.y, s1);
                s1 = fmaf(n[6], a1.z, s1); s1 = fmaf(n[7], a1.w, s1); s1 = fmaf(n[8], a2.x, s1);
                s2 = fmaf(n[0], b0.x, s2); s2 = fmaf(n[1], b0.y, s2); s2 = fmaf(n[2], b0.z, s2);
                s2 = fmaf(n[3], b0.w, s2); s2 = fmaf(n[4], b1.x, s2); s2 = fmaf(n[5], b1.y, s2);
                s2 = fmaf(n[6], b1.z, s2); s2 = fmaf(n[7], b1.w, s2); s2 = fmaf(n[8], b2.x, s2);
                pg[r]     += s1;
                pg[4 + r] += s2;
            }
        }
        #pragma unroll
        for (int i = 0; i < 8; ++i) ga[i] += pg[i];

        #pragma unroll
        for (int i = 0; i < NPF; ++i) {
            const int e = tid + i * 256;
            if (e < CHUNK_ELEMS) sx[buf ^ 1][e] = pf[i];
        }
        __syncthreads();
    }

    int r1 = 0, r2 = 0;
    {
        float m = ga[0];
        #pragma unroll
        for (int r = 1; r < 4; ++r) if (ga[r] > m) { m = ga[r]; r1 = r; }
        float m2 = ga[4];
        #pragma unroll
        for (int r = 1; r < 4; ++r) if (ga[4 + r] > m2) { m2 = ga[4 + r]; r2 = r; }
    }

    // ================= PASS 2: routed depthwise + 1x1 =================
    // NOTE: y[] is ONLY ever indexed by compile-time constants (rule #20:
    // a single runtime index — like the removed y[c] CA-fusion — demotes
    // the whole array to scratch => GBs of spill traffic; rounds 2-4 bug).
    float y[Cx];
    #pragma unroll
    for (int o = 0; o < Cx; ++o) y[o] = 0.f;

    #pragma unroll 1
    for (int ch = 0; ch < NCHUNK; ++ch) {
        const int buf = ch & 1;     // continues pass-1 parity: chunk0 is in sx[0]

        float pf[NPF];
        if (ch < NCHUNK - 1) {
            const float* src = xb + (size_t)(ch + 1) * CCH * HWx;
            #pragma unroll
            for (int i = 0; i < NPF; ++i)
                pf[i] = (vmask >> i & 1u) ? src[goff[i]] : 0.f;
        }

        #pragma unroll
        for (int cc = 0; cc < CCH; ++cc) {
            const int c = ch * CCH + cc;
            float n[9];
            #pragma unroll
            for (int kh = 0; kh < 3; ++kh)
                #pragma unroll
                for (int kw = 0; kw < 3; ++kw)
                    n[kh * 3 + kw] = sx[buf][cc * CPLANE + (ty + kh) * HALO_W + (tx + kw)];

            float dw = 0.f;
            #pragma unroll
            for (int k = 0; k < 9; ++k)
                dw = fmaf(n[k], skern[c * 36 + k * 4 + r1], dw);
            const float routed = dw > 0.f ? dw : 0.1f * dw;

            const float4* cwv = (const float4*)(scw + c * 64);   // uniform b128 broadcasts
            #pragma unroll
            for (int q = 0; q < 16; ++q) {
                const float4 w4 = cwv[q];
                y[q * 4 + 0] = fmaf(w4.x, routed, y[q * 4 + 0]);
                y[q * 4 + 1] = fmaf(w4.y, routed, y[q * 4 + 1]);
                y[q * 4 + 2] = fmaf(w4.z, routed, y[q * 4 + 2]);
                y[q * 4 + 3] = fmaf(w4.w, routed, y[q * 4 + 3]);
            }
        }

        if (ch < NCHUNK - 1) {
            #pragma unroll
            for (int i = 0; i < NPF; ++i) {
                const int e = tid + i * 256;
                if (e < CHUNK_ELEMS) sx[buf ^ 1][e] = pf[i];
            }
            __syncthreads();
        }
    }

    // --- epilogue: bias + CA branch (x center re-read, round-1 proven) + store ---
    const int hh = h0 + ty;
    const int ww = w0 + tx;
    float* op = out + (size_t)b * Cx * HWx + hh * Wx + ww;
    const float* xp = xb + hh * Wx + ww;
    #pragma unroll
    for (int o = 0; o < Cx; ++o) {
        const float v = y[o] + convb[o] + xp[(size_t)o * HWx] * satt[o * 4 + r2];
        op[(size_t)o * HWx] = v;
    }
}

extern "C" void kernel_launch(void* const* d_in, const int* in_sizes, int n_in,
                              void* d_out, int out_size, void* d_ws, size_t ws_size,
                              hipStream_t stream) {
    const float* x0     = (const float*)d_in[0];
    const float* x_deg  = (const float*)d_in[1];
    const float* kw1    = (const float*)d_in[2];
    const float* kw2    = (const float*)d_in[3];
    const float* convw  = (const float*)d_in[4];
    const float* convb  = (const float*)d_in[5];
    const float* ca_w1  = (const float*)d_in[6];
    const float* ca_w2  = (const float*)d_in[7];
    const float* g1w    = (const float*)d_in[8];
    const float* g1b    = (const float*)d_in[9];
    const float* g2w    = (const float*)d_in[10];
    const float* g2b    = (const float*)d_in[11];
    float* outp = (float*)d_out;
    float* wsf  = (float*)d_ws;

    da_prep<<<Bx + 1, 256, 0, stream>>>(x_deg, kw1, kw2, convw, ca_w1, ca_w2,
                                        g1w, g2w, wsf);

    dim3 grid(Wx / TW, Hx / TH, Bx);   // 4 x 16 x 16 = 1024 blocks
    da_main<<<grid, 256, 0, stream>>>(x0, wsf, g1b, g2b, convb, outp);
}

// Round 6
// 270.609 us; speedup vs baseline: 13.3409x; 13.3409x over previous
//
#include <hip/hip_runtime.h>
#include <math.h>

#define Bx 16
#define Cx 64
#define Hx 128
#define Wx 128
#define HWx (Hx * Wx)

#define TW 32
#define TH 8
#define CCH 8
#define HALO_W (TW + 2)
#define HALO_H (TH + 2)
#define CPLANE (HALO_H * HALO_W)          // 340
#define CHUNK_ELEMS (CCH * CPLANE)        // 2720
#define NCHUNK (Cx / CCH)                 // 8

// workspace layout (float offsets)
#define WS_CWT   0                         // cwT[c*64+o]            4096
#define WS_GPACK 4096                      // gpack12[c*96+rg*12+k]  6144  (rg=r*2+g)
#define WS_KERN  10240                     // per-b [c*36+k*4+g]     16*2304
#define WS_ATT   47104                     // per-b [c*4+r]          16*256

// ---------------- prep: hypernetwork + weight repacking (unchanged, passing) ----------------
__global__ __launch_bounds__(256)
void da_prep(const float* __restrict__ x_deg,
             const float* __restrict__ kw1,
             const float* __restrict__ kw2,
             const float* __restrict__ convw,
             const float* __restrict__ ca_w1,
             const float* __restrict__ ca_w2,
             const float* __restrict__ g1w,
             const float* __restrict__ g2w,
             float* __restrict__ ws)
{
    const int b = blockIdx.x;
    const int tid = threadIdx.x;

    if (b == Bx) {
        for (int i = tid; i < 4096; i += 256) {           // cwT[c*64+o] = convw[o*64+c]
            const int o = i >> 6, c = i & 63;
            ws[WS_CWT + c * 64 + o] = convw[o * 64 + c];
        }
        for (int i = tid; i < 6144; i += 256) {           // gpack12[c][rg=r*2+g][12]
            const int c = i / 96;
            int rem = i - c * 96;
            const int rg = rem / 12;
            const int k  = rem - rg * 12;
            const int r = rg >> 1;
            const int g = rg & 1;
            const float* src = g ? g2w : g1w;
            ws[WS_GPACK + i] = (k < 9) ? src[(r * Cx + c) * 9 + k] : 0.f;
        }
        return;
    }

    __shared__ float h1[16];
    __shared__ float a1[16];
    if (tid < 32) {
        const int j = tid & 15;
        const float* wsrc = (tid < 16) ? (kw1 + j * Cx) : (ca_w1 + j * Cx);
        float acc = 0.f;
        #pragma unroll 8
        for (int c = 0; c < Cx; ++c) acc = fmaf(x_deg[b * Cx + c], wsrc[c], acc);
        acc = acc > 0.f ? acc : 0.1f * acc;               // leaky_relu 0.1
        if (tid < 16) h1[j] = acc; else a1[j] = acc;
    }
    __syncthreads();

    for (int o4 = tid; o4 < 4 * 576; o4 += 256) {
        const int g = o4 / 576;
        const int o = o4 - g * 576;
        float acc = 0.f;
        #pragma unroll
        for (int i = 0; i < 4; ++i)
            acc = fmaf(h1[g * 4 + i], kw2[(g * 576 + o) * 4 + i], acc);
        const int c = o / 9;
        const int k = o - c * 9;
        ws[WS_KERN + b * 2304 + c * 36 + k * 4 + g] = acc;
    }
    {
        const int r = tid >> 6;
        const int c = tid & 63;
        float acc = 0.f;
        #pragma unroll
        for (int i = 0; i < 4; ++i)
            acc = fmaf(a1[r * 4 + i], ca_w2[(r * Cx + c) * 4 + i], acc);
        ws[WS_ATT + b * 256 + c * 4 + r] = 1.f / (1.f + expf(-acc));
    }
}

// ---------------- main fused kernel: round-0 skeleton + LDS weights ----------------
// Round-0 (375us, 68 VGPR, zero scratch) is the only structure the allocator
// handled cleanly. ONE change: weights read from LDS (staged in prologue)
// instead of SMEM latency chains. NO prefetch arrays, NO state except
// ga[8]/y[64] across barriers, ALL register arrays statically indexed.
__global__ __launch_bounds__(256, 2)
void da_main(const float* __restrict__ x0,
             const float* __restrict__ ws,
             const float* __restrict__ g1b,
             const float* __restrict__ g2b,
             const float* __restrict__ convb,
             float* __restrict__ out)
{
    const int b  = blockIdx.z;
    const int h0 = blockIdx.y * TH;
    const int w0 = blockIdx.x * TW;
    const int tid = threadIdx.x;
    const int tx = tid & (TW - 1);
    const int ty = tid >> 5;

    __shared__ float sx[CHUNK_ELEMS];                 // single-buffer x chunk (halo)
    __shared__ __align__(16) float sgp[6144];         // guide weights [c][rg][12]
    __shared__ __align__(16) float scw[4096];         // cwT [c][o]
    __shared__ float skern[2304];                     // [c][k][r]
    __shared__ float satt[256];                       // [c][r]

    const float* xb  = x0 + (size_t)b * Cx * HWx;
    const float* kws = ws + WS_KERN + b * 2304;
    const float* aws = ws + WS_ATT  + b * 256;

    // --- prologue: stage all weights into LDS (transient regs only) ---
    #pragma unroll 1
    for (int j = 0; j < 24; ++j) sgp[tid + j * 256] = ws[WS_GPACK + tid + j * 256];
    #pragma unroll 1
    for (int j = 0; j < 16; ++j) scw[tid + j * 256] = ws[WS_CWT + tid + j * 256];
    #pragma unroll 1
    for (int j = 0; j < 9; ++j)  skern[tid + j * 256] = kws[tid + j * 256];
    satt[tid] = aws[tid];
    // visibility covered by the first staging barrier below

    // ================= PASS 1: guide convs -> argmax =================
    float ga[8];
    #pragma unroll
    for (int r = 0; r < 4; ++r) { ga[r] = g1b[r]; ga[4 + r] = g2b[r]; }

    #pragma unroll 1
    for (int ch = 0; ch < NCHUNK; ++ch) {
        __syncthreads();
        #pragma unroll 1
        for (int e = tid; e < CHUNK_ELEMS; e += 256) {   // round-0 inline staging
            const int cc  = e / CPLANE;
            const int rem = e - cc * CPLANE;
            const int row = rem / HALO_W;
            const int col = rem - row * HALO_W;
            const int gh = h0 - 1 + row;
            const int gw = w0 - 1 + col;
            float v = 0.f;
            if ((unsigned)gh < Hx && (unsigned)gw < Wx)
                v = xb[(size_t)(ch * CCH + cc) * HWx + gh * Wx + gw];
            sx[e] = v;
        }
        __syncthreads();

        float pg[8] = {0.f, 0.f, 0.f, 0.f, 0.f, 0.f, 0.f, 0.f};
        #pragma unroll
        for (int cc = 0; cc < CCH; ++cc) {
            const int c = ch * CCH + cc;
            float n[9];
            #pragma unroll
            for (int kh = 0; kh < 3; ++kh)
                #pragma unroll
                for (int kw = 0; kw < 3; ++kw)
                    n[kh * 3 + kw] = sx[cc * CPLANE + (ty + kh) * HALO_W + (tx + kw)];
            const float4* gpv = (const float4*)(sgp + c * 96);   // uniform b128 broadcast
            #pragma unroll
            for (int rg = 0; rg < 8; ++rg) {          // rg = r*2+g; <=3 float4 live
                const float4 q0 = gpv[rg * 3 + 0];
                const float4 q1 = gpv[rg * 3 + 1];
                const float4 q2 = gpv[rg * 3 + 2];
                float s = 0.f;                        // k-ascending, bit-identical chain
                s = fmaf(n[0], q0.x, s); s = fmaf(n[1], q0.y, s); s = fmaf(n[2], q0.z, s);
                s = fmaf(n[3], q0.w, s); s = fmaf(n[4], q1.x, s); s = fmaf(n[5], q1.y, s);
                s = fmaf(n[6], q1.z, s); s = fmaf(n[7], q1.w, s); s = fmaf(n[8], q2.x, s);
                pg[(rg >> 1) + (rg & 1) * 4] += s;    // static index (unrolled rg)
            }
        }
        #pragma unroll
        for (int i = 0; i < 8; ++i) ga[i] += pg[i];
    }

    int r1 = 0, r2 = 0;
    {
        float m = ga[0];
        #pragma unroll
        for (int r = 1; r < 4; ++r) if (ga[r] > m) { m = ga[r]; r1 = r; }   // first-max ties
        float m2 = ga[4];
        #pragma unroll
        for (int r = 1; r < 4; ++r) if (ga[4 + r] > m2) { m2 = ga[4 + r]; r2 = r; }
    }

    // ================= PASS 2: routed depthwise + 1x1 =================
    float y[Cx];
    #pragma unroll
    for (int o = 0; o < Cx; ++o) y[o] = 0.f;

    #pragma unroll 1
    for (int ch = 0; ch < NCHUNK; ++ch) {
        __syncthreads();
        #pragma unroll 1
        for (int e = tid; e < CHUNK_ELEMS; e += 256) {
            const int cc  = e / CPLANE;
            const int rem = e - cc * CPLANE;
            const int row = rem / HALO_W;
            const int col = rem - row * HALO_W;
            const int gh = h0 - 1 + row;
            const int gw = w0 - 1 + col;
            float v = 0.f;
            if ((unsigned)gh < Hx && (unsigned)gw < Wx)
                v = xb[(size_t)(ch * CCH + cc) * HWx + gh * Wx + gw];
            sx[e] = v;
        }
        __syncthreads();

        #pragma unroll
        for (int cc = 0; cc < CCH; ++cc) {
            const int c = ch * CCH + cc;
            float n[9];
            #pragma unroll
            for (int kh = 0; kh < 3; ++kh)
                #pragma unroll
                for (int kw = 0; kw < 3; ++kw)
                    n[kh * 3 + kw] = sx[cc * CPLANE + (ty + kh) * HALO_W + (tx + kw)];

            float dw = 0.f;
            #pragma unroll
            for (int k = 0; k < 9; ++k)
                dw = fmaf(n[k], skern[c * 36 + k * 4 + r1], dw);
            const float routed = dw > 0.f ? dw : 0.1f * dw;

            const float4* cwv = (const float4*)(scw + c * 64);   // uniform b128 broadcast
            #pragma unroll
            for (int q = 0; q < 16; ++q) {            // load-use immediately, y static
                const float4 w4 = cwv[q];
                y[q * 4 + 0] = fmaf(w4.x, routed, y[q * 4 + 0]);
                y[q * 4 + 1] = fmaf(w4.y, routed, y[q * 4 + 1]);
                y[q * 4 + 2] = fmaf(w4.z, routed, y[q * 4 + 2]);
                y[q * 4 + 3] = fmaf(w4.w, routed, y[q * 4 + 3]);
            }
        }
    }

    // --- epilogue: bias + CA branch (x center re-read, round-0 proven) + store ---
    const int hh = h0 + ty;
    const int ww = w0 + tx;
    float* op = out + (size_t)b * Cx * HWx + hh * Wx + ww;
    const float* xp = xb + hh * Wx + ww;
    #pragma unroll
    for (int o = 0; o < Cx; ++o) {
        const float v = y[o] + convb[o] + xp[(size_t)o * HWx] * satt[o * 4 + r2];
        op[(size_t)o * HWx] = v;
    }
}

extern "C" void kernel_launch(void* const* d_in, const int* in_sizes, int n_in,
                              void* d_out, int out_size, void* d_ws, size_t ws_size,
                              hipStream_t stream) {
    const float* x0     = (const float*)d_in[0];
    const float* x_deg  = (const float*)d_in[1];
    const float* kw1    = (const float*)d_in[2];
    const float* kw2    = (const float*)d_in[3];
    const float* convw  = (const float*)d_in[4];
    const float* convb  = (const float*)d_in[5];
    const float* ca_w1  = (const float*)d_in[6];
    const float* ca_w2  = (const float*)d_in[7];
    const float* g1w    = (const float*)d_in[8];
    const float* g1b    = (const float*)d_in[9];
    const float* g2w    = (const float*)d_in[10];
    const float* g2b    = (const float*)d_in[11];
    float* outp = (float*)d_out;
    float* wsf  = (float*)d_ws;

    da_prep<<<Bx + 1, 256, 0, stream>>>(x_deg, kw1, kw2, convw, ca_w1, ca_w2,
                                        g1w, g2w, wsf);

    dim3 grid(Wx / TW, Hx / TH, Bx);   // 4 x 16 x 16 = 1024 blocks
    da_main<<<grid, 256, 0, stream>>>(x0, wsf, g1b, g2b, convb, outp);
}